// Round 3
// baseline (228.954 us; speedup 1.0000x reference)
//
#include <hip/hip_runtime.h>
#include <math.h>

#ifndef M_PI
#define M_PI 3.14159265358979323846
#endif

#define NBLK  1024   // edge chunks / scatter blocks
#define CHUNK 8192   // max edges per chunk (LDS payload buffer size)
#define BSZ   512    // particles per bucket
#define BSH   9      // log2(BSZ)
#define NBK   512    // max buckets supported by LDS arrays

// ---------------------------------------------------------------- detect ----
// neighbors dtype probe: int64 => odd 32-bit words (high halves) are all 0.
__global__ void detect_idx_width(const unsigned* __restrict__ words,
                                 int* __restrict__ flag) {
    if (blockIdx.x == 0 && threadIdx.x == 0) {
        int is64 = 1;
#pragma unroll 1
        for (int k = 1; k < 2048; k += 2) {
            if (words[k] != 0u) { is64 = 0; break; }
        }
        *flag = is64;
    }
}

// ------------------------------------------------------------- pre table ----
// pre[p] = { fc*restDensity*area, density*restDensity, vel.x, vel.y }
__global__ __launch_bounds__(256) void precompute_particle(
    const float* __restrict__ fc_p, const float* __restrict__ area,
    const float* __restrict__ density, const float* __restrict__ restDensity,
    const float* __restrict__ velocity, float4* __restrict__ pre, int N)
{
    int p = blockIdx.x * 256 + threadIdx.x;
    if (p >= N) return;
    const float fc = fc_p[0];
    const float rD = restDensity[p];
    const float2 v = ((const float2*)velocity)[p];
    pre[p] = make_float4(fc * rD * area[p], density[p] * rD, v.x, v.y);
}

// ----------------------------------------------------------------- count ----
// table layout: [block][bucket] (row-major, coalesced writes per block)
__global__ __launch_bounds__(256) void pass_count(
    const void* __restrict__ nbr, const int* __restrict__ flag,
    unsigned* __restrict__ table, int E, int chunk, int NBnum)
{
    __shared__ unsigned cnt[NBK];
    for (int t = threadIdx.x; t < NBnum; t += 256) cnt[t] = 0u;
    __syncthreads();
    const int is64 = *flag;
    const long long s = (long long)blockIdx.x * chunk;
    long long e = s + chunk; if (e > E) e = E;
    if (is64) {
        const long long* ni = (const long long*)nbr;
        for (long long idx = s + threadIdx.x; idx < e; idx += 256)
            atomicAdd(&cnt[((int)ni[idx]) >> BSH], 1u);
    } else {
        const int* ni = (const int*)nbr;
        for (long long idx = s + threadIdx.x; idx < e; idx += 256)
            atomicAdd(&cnt[ni[idx] >> BSH], 1u);
    }
    __syncthreads();
    for (int t = threadIdx.x; t < NBnum; t += 256)
        table[(size_t)blockIdx.x * NBnum + t] = cnt[t];
}

// ------------------------------------------------- scan over blocks ---------
// grid = NBnum blocks of NBLK(=1024) threads; column k of table (strided,
// L2-resident) -> in-place exclusive scan; column total -> btot[k].
__global__ __launch_bounds__(NBLK) void scan_blocks(
    unsigned* __restrict__ table, unsigned* __restrict__ btot, int NBnum)
{
    __shared__ unsigned buf[NBLK];
    const int t = threadIdx.x;
    const int k = blockIdx.x;
    buf[t] = table[(size_t)t * NBnum + k];
    __syncthreads();
    for (int o = 1; o < NBLK; o <<= 1) {
        unsigned v = (t >= o) ? buf[t - o] : 0u;
        __syncthreads();
        buf[t] += v;
        __syncthreads();
    }
    table[(size_t)t * NBnum + k] = (t == 0) ? 0u : buf[t - 1];
    if (t == NBLK - 1) btot[k] = buf[t];
}

// -------------------------------------------------- scan bucket totals ------
// 1 block of NBnum threads. bstart[NBnum] = E sentinel.
__global__ void scan_buckets(const unsigned* __restrict__ btot,
                             unsigned* __restrict__ bstart, int NBnum)
{
    __shared__ unsigned buf[1024];
    const int t = threadIdx.x;
    buf[t] = btot[t];
    __syncthreads();
    for (int o = 1; o < NBnum; o <<= 1) {
        unsigned v = (t >= o) ? buf[t - o] : 0u;
        __syncthreads();
        buf[t] += v;
        __syncthreads();
    }
    bstart[t] = (t == 0) ? 0u : buf[t - 1];
    if (t == NBnum - 1) bstart[NBnum] = buf[t];
}

// --------------------------------------------------------------- scatter ----
// LDS-staged: histogram -> local scan -> place into LDS sorted buffer ->
// run-wise linear write-out (full cache lines, each line written once).
// payload.x = j | (i_local << 22)   (requires N <= 2^22), payload.y = bits(q)
__global__ __launch_bounds__(256) void pass_scatter(
    const void* __restrict__ nbr, const float* __restrict__ rad,
    const int* __restrict__ flag, const unsigned* __restrict__ table,
    const unsigned* __restrict__ bstart, int2* __restrict__ jq,
    int E, int chunk, int NBnum)
{
    __shared__ int2 buf[CHUNK];          // 64 KB payload staging
    __shared__ unsigned cur[NBK];        // counts -> inclusive scan -> cursors
    __shared__ unsigned loff[NBK + 1];   // exclusive local offsets + sentinel
    __shared__ unsigned dst[NBK];        // global dest base per bucket

    const int b = blockIdx.x;
    const long long s = (long long)b * chunk;
    long long e = s + chunk; if (e > E) e = E;
    const int n = (int)(e - s);
    if (n <= 0) return;                  // uniform across block
    const int tid = threadIdx.x;

    for (int k = tid; k < NBnum; k += 256) cur[k] = 0u;
    __syncthreads();

    const int is64 = *flag;
    // phase A: histogram of i
    if (is64) {
        const long long* ni = (const long long*)nbr;
        for (long long idx = s + tid; idx < e; idx += 256)
            atomicAdd(&cur[((int)ni[idx]) >> BSH], 1u);
    } else {
        const int* ni = (const int*)nbr;
        for (long long idx = s + tid; idx < e; idx += 256)
            atomicAdd(&cur[ni[idx] >> BSH], 1u);
    }
    __syncthreads();

    // phase A2: inclusive Hillis-Steele scan of cur[0..NBnum), 2 elems/thread
    for (int o = 1; o < NBnum; o <<= 1) {
        const int t0 = tid, t1 = tid + 256;
        unsigned v0 = (t0 < NBnum) ? cur[t0] : 0u;
        unsigned m0 = (t0 >= o && t0 < NBnum) ? cur[t0 - o] : 0u;
        unsigned v1 = (t1 < NBnum) ? cur[t1] : 0u;
        unsigned m1 = (t1 >= o && t1 < NBnum) ? cur[t1 - o] : 0u;
        __syncthreads();
        if (t0 < NBnum) cur[t0] = v0 + m0;
        if (t1 < NBnum) cur[t1] = v1 + m1;
        __syncthreads();
    }
    // exclusive offsets, global dest bases
    for (int k = tid; k < NBnum; k += 256) {
        loff[k] = k ? cur[k - 1] : 0u;
        dst[k] = bstart[k] + table[(size_t)b * NBnum + k];
    }
    if (tid == 0) loff[NBnum] = (unsigned)n;
    __syncthreads();
    for (int k = tid; k < NBnum; k += 256) cur[k] = loff[k];
    __syncthreads();

    // phase B: place payloads at locally-sorted LDS positions
    if (is64) {
        const long long* ni = (const long long*)nbr;
        const long long* nj = ni + E;
        for (long long idx = s + tid; idx < e; idx += 256) {
            int i = (int)ni[idx];
            int j = (int)nj[idx];
            float q = rad[idx];
            unsigned pos = atomicAdd(&cur[i >> BSH], 1u);
            buf[pos] = make_int2(j | ((i & (BSZ - 1)) << 22),
                                 __float_as_int(q));
        }
    } else {
        const int* ni = (const int*)nbr;
        const int* nj = ni + E;
        for (long long idx = s + tid; idx < e; idx += 256) {
            int i = ni[idx];
            int j = nj[idx];
            float q = rad[idx];
            unsigned pos = atomicAdd(&cur[i >> BSH], 1u);
            buf[pos] = make_int2(j | ((i & (BSZ - 1)) << 22),
                                 __float_as_int(q));
        }
    }
    __syncthreads();

    // phase C: linear write-out; binary search bucket of local index t
    for (int t = tid; t < n; t += 256) {
        int lo = 0, hi = NBnum;
        while (hi - lo > 1) {
            int mid = (lo + hi) >> 1;
            if (loff[mid] <= (unsigned)t) lo = mid; else hi = mid;
        }
        jq[dst[lo] + ((unsigned)t - loff[lo])] = buf[t];
    }
}

// ---------------------------------------------------------------- reduce ----
__global__ __launch_bounds__(256) void pass_reduce(
    const int2* __restrict__ jq, const float4* __restrict__ pre,
    const unsigned* __restrict__ bstart, const float* __restrict__ support_p,
    float2* __restrict__ out, int N)
{
    __shared__ float4 plds[BSZ];
    __shared__ float2 acc[BSZ];
    const int k = blockIdx.x;
    const int base = k << BSH;
    for (int t = threadIdx.x; t < BSZ; t += 256) {
        int p = base + t;
        plds[t] = (p < N) ? pre[p] : make_float4(0.f, 0.f, 0.f, 0.f);
        acc[t] = make_float2(0.f, 0.f);
    }
    __syncthreads();
    const float h = support_p[0];
    const float C = 7.0f / ((float)M_PI * h * h);
    const unsigned s = bstart[k];
    const unsigned e = bstart[k + 1];
    for (unsigned idx = s + threadIdx.x; idx < e; idx += 256) {
        const int2 pk = jq[idx];
        const int j = pk.x & ((1 << 22) - 1);
        const int il = (pk.x >> 22) & (BSZ - 1);
        const float q = __int_as_float(pk.y);
        const float4 pj = pre[j];
        const float4 pi = plds[il];
        const float b = fmaxf(1.0f - q, 0.0f);
        const float b2 = b * b;
        const float w = C * (b2 * b2) * fmaf(4.0f, q, 1.0f);
        const float sc = pj.x * 2.0f * w / (pi.y + pj.y);
        atomicAdd(&acc[il].x, sc * (pj.z - pi.z));
        atomicAdd(&acc[il].y, sc * (pj.w - pi.w));
    }
    __syncthreads();
    for (int t = threadIdx.x; t < BSZ; t += 256) {
        int p = base + t;
        if (p < N) out[p] = acc[t];
    }
}

// ------------------------------------------------- fallback (atomic path) ---
__global__ __launch_bounds__(256) void xsph_edge_kernel(
    const float* __restrict__ fc_p, const float* __restrict__ area,
    const float* __restrict__ density, const float* __restrict__ restDensity,
    const float* __restrict__ velocity, const float* __restrict__ rad,
    const void* __restrict__ nbr, const float* __restrict__ support_p,
    const int* __restrict__ flag, float* __restrict__ out, int E)
{
    const int is64 = *flag;
    const float fc = fc_p[0];
    const float h = support_p[0];
    const float C = 7.0f / ((float)M_PI * h * h);
    const long long e0 =
        (long long)(blockIdx.x * (long long)blockDim.x + threadIdx.x) * 4;
    if (e0 >= (long long)E) return;
    int ii[4], jj[4];
    if (is64) {
        const long long* ni = (const long long*)nbr;
        const long long* nj = ni + E;
#pragma unroll
        for (int k = 0; k < 4; ++k) { ii[k] = (int)ni[e0 + k]; jj[k] = (int)nj[e0 + k]; }
    } else {
        const int* ni = (const int*)nbr;
        const int* nj = ni + E;
        int4 iv = *(const int4*)(ni + e0);
        int4 jv = *(const int4*)(nj + e0);
        ii[0] = iv.x; ii[1] = iv.y; ii[2] = iv.z; ii[3] = iv.w;
        jj[0] = jv.x; jj[1] = jv.y; jj[2] = jv.z; jj[3] = jv.w;
    }
    float4 qv = *(const float4*)(rad + e0);
    float qq[4] = {qv.x, qv.y, qv.z, qv.w};
#pragma unroll
    for (int k = 0; k < 4; ++k) {
        const int i = ii[k], j = jj[k];
        const float rDi = restDensity[i], rDj = restDensity[j];
        const float fac = fc * rDj * area[j];
        const float rho_i = density[i] * rDi, rho_j = density[j] * rDj;
        const float2 vi = *(const float2*)(velocity + 2 * i);
        const float2 vj = *(const float2*)(velocity + 2 * j);
        const float q = qq[k];
        const float b = fmaxf(1.0f - q, 0.0f);
        const float b2 = b * b;
        const float w = C * (b2 * b2) * fmaf(4.0f, q, 1.0f);
        const float s = fac * 2.0f * w / (rho_i + rho_j);
        unsafeAtomicAdd(&out[2 * i],     s * (vj.x - vi.x));
        unsafeAtomicAdd(&out[2 * i + 1], s * (vj.y - vi.y));
    }
}

// ------------------------------------------------------------------ host ----
extern "C" void kernel_launch(void* const* d_in, const int* in_sizes, int n_in,
                              void* d_out, int out_size, void* d_ws, size_t ws_size,
                              hipStream_t stream) {
    const float* fc          = (const float*)d_in[0];
    const float* area        = (const float*)d_in[1];
    const float* density     = (const float*)d_in[2];
    const float* restDensity = (const float*)d_in[3];
    const float* velocity    = (const float*)d_in[4];
    const float* rad         = (const float*)d_in[5];
    const void*  nbr         = d_in[6];
    const float* support     = (const float*)d_in[7];

    const int N = in_sizes[1];
    const int E = in_sizes[5];
    const int NBnum = (N + BSZ - 1) / BSZ;
    const int chunk = (int)(((long long)E + NBLK - 1) / NBLK);

    // ---- workspace layout (16B-aligned sections) ----
    char* ws = (char*)d_ws;
    size_t off = 0;
    int* flag = (int*)(ws + off);               off += 16;
    float4* pre = (float4*)(ws + off);          off += (size_t)N * 16;
    unsigned* table = (unsigned*)(ws + off);    off += (size_t)NBLK * NBnum * 4;
    off = (off + 15) & ~(size_t)15;
    unsigned* btot = (unsigned*)(ws + off);     off += (size_t)NBnum * 4;
    off = (off + 15) & ~(size_t)15;
    unsigned* bstart = (unsigned*)(ws + off);   off += (size_t)(NBnum + 1) * 4;
    off = (off + 15) & ~(size_t)15;
    int2* jq = (int2*)(ws + off);               off += (size_t)E * 8;
    const size_t need = off;

    detect_idx_width<<<1, 1, 0, stream>>>((const unsigned*)nbr, flag);

    const bool can_sort =
        (ws_size >= need) && (NBnum <= NBK) && (N <= (1 << 22)) &&
        (chunk <= CHUNK) && (E > 0);

    if (can_sort) {
        precompute_particle<<<(N + 255) / 256, 256, 0, stream>>>(
            fc, area, density, restDensity, velocity, pre, N);
        pass_count<<<NBLK, 256, 0, stream>>>(nbr, flag, table, E, chunk, NBnum);
        scan_blocks<<<NBnum, NBLK, 0, stream>>>(table, btot, NBnum);
        scan_buckets<<<1, NBnum, 0, stream>>>(btot, bstart, NBnum);
        pass_scatter<<<NBLK, 256, 0, stream>>>(nbr, rad, flag, table, bstart,
                                               jq, E, chunk, NBnum);
        pass_reduce<<<NBnum, 256, 0, stream>>>(jq, pre, bstart, support,
                                               (float2*)d_out, N);
    } else {
        hipMemsetAsync(d_out, 0, (size_t)out_size * sizeof(float), stream);
        const int threads = 256;
        const long long nthreads = ((long long)E + 3) / 4;
        const int blocks = (int)((nthreads + threads - 1) / threads);
        xsph_edge_kernel<<<blocks, threads, 0, stream>>>(
            fc, area, density, restDensity, velocity, rad, nbr, support, flag,
            (float*)d_out, E);
    }
}

// Round 4
// 227.992 us; speedup vs baseline: 1.0042x; 1.0042x over previous
//
#include <hip/hip_runtime.h>
#include <math.h>

#ifndef M_PI
#define M_PI 3.14159265358979323846
#endif

#define NBLK  2048   // edge chunks (count/scatter blocks)
#define CHUNK 4096   // max edges per chunk (LDS payload buffer)
#define BSZ   512    // particles per bucket
#define BSH   9      // log2(BSZ)
#define NBK   512    // max buckets supported by LDS arrays

#define SCAN_GB   16                 // buckets per scan block
#define SCAN_TH   512                // threads in scan block
#define SCAN_ROWS (NBLK / SCAN_TH)   // rows per thread (4)

// ---------------------------------------------------------------- detect ----
// neighbors dtype probe: int64 => odd 32-bit words (high halves) are all 0.
__global__ void detect_idx_width(const unsigned* __restrict__ words,
                                 int* __restrict__ flag) {
    if (blockIdx.x == 0 && threadIdx.x == 0) {
        int is64 = 1;
#pragma unroll 1
        for (int k = 1; k < 2048; k += 2) {
            if (words[k] != 0u) { is64 = 0; break; }
        }
        *flag = is64;
    }
}

// ------------------------------------------------------------- pre table ----
// pre[p] = { fc*restDensity*area, density*restDensity, vel.x, vel.y }
__global__ __launch_bounds__(256) void precompute_particle(
    const float* __restrict__ fc_p, const float* __restrict__ area,
    const float* __restrict__ density, const float* __restrict__ restDensity,
    const float* __restrict__ velocity, float4* __restrict__ pre, int N)
{
    int p = blockIdx.x * 256 + threadIdx.x;
    if (p >= N) return;
    const float fc = fc_p[0];
    const float rD = restDensity[p];
    const float2 v = ((const float2*)velocity)[p];
    pre[p] = make_float4(fc * rD * area[p], density[p] * rD, v.x, v.y);
}

// ----------------------------------------------------------------- count ----
// table layout: [block][bucket] (row-major; coalesced row write per block).
// NOTE: must write the row even for empty chunks (scan expects NBLK rows).
__global__ __launch_bounds__(256) void pass_count(
    const void* __restrict__ nbr, const int* __restrict__ flag,
    unsigned* __restrict__ table, int E, int chunk, int NBnum)
{
    __shared__ unsigned cnt[NBK];
    for (int t = threadIdx.x; t < NBnum; t += 256) cnt[t] = 0u;
    __syncthreads();
    const int is64 = *flag;
    const long long s = (long long)blockIdx.x * chunk;
    long long e = s + chunk; if (e > E) e = E;
    if (is64) {
        const long long* ni = (const long long*)nbr;
        for (long long idx = s + threadIdx.x; idx < e; idx += 256)
            atomicAdd(&cnt[((int)ni[idx]) >> BSH], 1u);
    } else {
        const int* ni = (const int*)nbr;
        for (long long idx = s + threadIdx.x; idx < e; idx += 256)
            atomicAdd(&cnt[ni[idx] >> BSH], 1u);
    }
    __syncthreads();
    for (int t = threadIdx.x; t < NBnum; t += 256)
        table[(size_t)blockIdx.x * NBnum + t] = cnt[t];
}

// ------------------------------------------------- scan over blocks ---------
// grid = ceil(NBnum/SCAN_GB) blocks x SCAN_TH threads. Each block scans
// SCAN_GB consecutive buckets (columns) over all NBLK rows with full-line
// (64B) reads/writes. Exclusive offsets -> toff, column totals -> btot.
// Counts in `table` are preserved.
__global__ __launch_bounds__(SCAN_TH) void scan_blocks(
    const unsigned* __restrict__ table, unsigned* __restrict__ toff,
    unsigned* __restrict__ btot, int NBnum)
{
    __shared__ unsigned sums[SCAN_TH][SCAN_GB + 1];  // pad 17: conflict-free
    const int t = threadIdx.x;
    const int k0 = blockIdx.x * SCAN_GB;
    unsigned v[SCAN_ROWS][SCAN_GB];
    unsigned loc[SCAN_GB];
#pragma unroll
    for (int g = 0; g < SCAN_GB; ++g) loc[g] = 0u;
#pragma unroll
    for (int r = 0; r < SCAN_ROWS; ++r) {
        const size_t row = (size_t)(t * SCAN_ROWS + r) * NBnum;
#pragma unroll
        for (int g = 0; g < SCAN_GB; ++g) {
            unsigned x = (k0 + g < NBnum) ? table[row + k0 + g] : 0u;
            v[r][g] = x;
            loc[g] += x;
        }
    }
#pragma unroll
    for (int g = 0; g < SCAN_GB; ++g) sums[t][g] = loc[g];
    __syncthreads();
    for (int o = 1; o < SCAN_TH; o <<= 1) {
        unsigned m[SCAN_GB];
#pragma unroll
        for (int g = 0; g < SCAN_GB; ++g) m[g] = (t >= o) ? sums[t - o][g] : 0u;
        __syncthreads();
#pragma unroll
        for (int g = 0; g < SCAN_GB; ++g) sums[t][g] += m[g];
        __syncthreads();
    }
    unsigned pre[SCAN_GB];
#pragma unroll
    for (int g = 0; g < SCAN_GB; ++g) pre[g] = t ? sums[t - 1][g] : 0u;
#pragma unroll
    for (int r = 0; r < SCAN_ROWS; ++r) {
        const size_t row = (size_t)(t * SCAN_ROWS + r) * NBnum;
#pragma unroll
        for (int g = 0; g < SCAN_GB; ++g) {
            if (k0 + g < NBnum) toff[row + k0 + g] = pre[g];
            pre[g] += v[r][g];
        }
    }
    if (t == SCAN_TH - 1) {
#pragma unroll
        for (int g = 0; g < SCAN_GB; ++g)
            if (k0 + g < NBnum) btot[k0 + g] = sums[t][g];
    }
}

// -------------------------------------------------- scan bucket totals ------
// 1 block of NBnum threads. bstart[NBnum] = E sentinel.
__global__ void scan_buckets(const unsigned* __restrict__ btot,
                             unsigned* __restrict__ bstart, int NBnum)
{
    __shared__ unsigned buf[1024];
    const int t = threadIdx.x;
    buf[t] = btot[t];
    __syncthreads();
    for (int o = 1; o < NBnum; o <<= 1) {
        unsigned v = (t >= o) ? buf[t - o] : 0u;
        __syncthreads();
        buf[t] += v;
        __syncthreads();
    }
    bstart[t] = (t == 0) ? 0u : buf[t - 1];
    if (t == NBnum - 1) bstart[NBnum] = buf[t];
}

// --------------------------------------------------------------- scatter ----
// Per chunk: load counts row (no i re-stream), local scan -> cursors, place
// payloads into LDS at locally-sorted positions, then run-wise linear
// write-out (dense lines). payload.x = j | i_local<<22, payload.y = bits(q).
// LDS = 32K buf + 2K cur + 2K dst = 36KB -> 4 blocks/CU.
__global__ __launch_bounds__(256) void pass_scatter(
    const void* __restrict__ nbr, const float* __restrict__ rad,
    const int* __restrict__ flag, const unsigned* __restrict__ table,
    const unsigned* __restrict__ toff, const unsigned* __restrict__ bstart,
    int2* __restrict__ jq, int E, int chunk, int NBnum)
{
    __shared__ int2 buf[CHUNK];      // 32 KB payload staging
    __shared__ unsigned cur[NBK];    // counts -> incl scan -> excl cursors -> incl ends
    __shared__ unsigned dst[NBK];    // global dest base per bucket

    const int b = blockIdx.x;
    const long long s = (long long)b * chunk;
    long long e = s + chunk; if (e > E) e = E;
    const int n = (int)(e - s);
    if (n <= 0) return;              // uniform across block
    const int tid = threadIdx.x;

    // load per-chunk counts + global dest bases
    for (int k = tid; k < NBnum; k += 256) {
        cur[k] = table[(size_t)b * NBnum + k];
        dst[k] = bstart[k] + toff[(size_t)b * NBnum + k];
    }
    __syncthreads();

    // inclusive Hillis-Steele scan of cur[0..NBnum), 2 elems/thread
    for (int o = 1; o < NBnum; o <<= 1) {
        const int t0 = tid, t1 = tid + 256;
        unsigned v0 = (t0 < NBnum) ? cur[t0] : 0u;
        unsigned m0 = (t0 >= o && t0 < NBnum) ? cur[t0 - o] : 0u;
        unsigned v1 = (t1 < NBnum) ? cur[t1] : 0u;
        unsigned m1 = (t1 >= o && t1 < NBnum) ? cur[t1 - o] : 0u;
        __syncthreads();
        if (t0 < NBnum) cur[t0] = v0 + m0;
        if (t1 < NBnum) cur[t1] = v1 + m1;
        __syncthreads();
    }
    // shift inclusive -> exclusive (cursor start positions)
    {
        const int t0 = tid, t1 = tid + 256;
        unsigned x0 = (t0 < NBnum) ? (t0 ? cur[t0 - 1] : 0u) : 0u;
        unsigned x1 = (t1 < NBnum) ? cur[t1 - 1] : 0u;
        __syncthreads();
        if (t0 < NBnum) cur[t0] = x0;
        if (t1 < NBnum) cur[t1] = x1;
        __syncthreads();
    }

    // phase B: stream edges, place payloads at locally-sorted LDS positions
    const int is64 = *flag;
    if (is64) {
        const long long* ni = (const long long*)nbr;
        const long long* nj = ni + E;
        for (long long idx = s + tid; idx < e; idx += 256) {
            int i = (int)ni[idx];
            int j = (int)nj[idx];
            float q = rad[idx];
            unsigned pos = atomicAdd(&cur[i >> BSH], 1u);
            buf[pos] = make_int2(j | ((i & (BSZ - 1)) << 22),
                                 __float_as_int(q));
        }
    } else {
        const int* ni = (const int*)nbr;
        const int* nj = ni + E;
        for (long long idx = s + tid; idx < e; idx += 256) {
            int i = ni[idx];
            int j = nj[idx];
            float q = rad[idx];
            unsigned pos = atomicAdd(&cur[i >> BSH], 1u);
            buf[pos] = make_int2(j | ((i & (BSZ - 1)) << 22),
                                 __float_as_int(q));
        }
    }
    __syncthreads();
    // now cur[k] == inclusive end of bucket k's local run

    // phase C: linear write-out; binary search smallest k with cur[k] > t
    for (int t = tid; t < n; t += 256) {
        int lo = 0, hi = NBnum - 1;
        while (lo < hi) {
            int mid = (lo + hi) >> 1;
            if (cur[mid] > (unsigned)t) hi = mid; else lo = mid + 1;
        }
        unsigned start = lo ? cur[lo - 1] : 0u;
        jq[dst[lo] + ((unsigned)t - start)] = buf[t];
    }
}

// ---------------------------------------------------------------- reduce ----
__global__ __launch_bounds__(512) void pass_reduce(
    const int2* __restrict__ jq, const float4* __restrict__ pre,
    const unsigned* __restrict__ bstart, const float* __restrict__ support_p,
    float2* __restrict__ out, int N)
{
    __shared__ float4 plds[BSZ];
    __shared__ float2 acc[BSZ];
    const int k = blockIdx.x;
    const int base = k << BSH;
    for (int t = threadIdx.x; t < BSZ; t += 512) {
        int p = base + t;
        plds[t] = (p < N) ? pre[p] : make_float4(0.f, 0.f, 0.f, 0.f);
        acc[t] = make_float2(0.f, 0.f);
    }
    __syncthreads();
    const float h = support_p[0];
    const float C = 7.0f / ((float)M_PI * h * h);
    const unsigned s = bstart[k];
    const unsigned e = bstart[k + 1];
    for (unsigned idx = s + threadIdx.x; idx < e; idx += 512) {
        const int2 pk = jq[idx];
        const int j = pk.x & ((1 << 22) - 1);
        const int il = (pk.x >> 22) & (BSZ - 1);
        const float q = __int_as_float(pk.y);
        const float4 pj = pre[j];
        const float4 pi = plds[il];
        const float b = fmaxf(1.0f - q, 0.0f);
        const float b2 = b * b;
        const float w = C * (b2 * b2) * fmaf(4.0f, q, 1.0f);
        const float sc = pj.x * 2.0f * w / (pi.y + pj.y);
        atomicAdd(&acc[il].x, sc * (pj.z - pi.z));
        atomicAdd(&acc[il].y, sc * (pj.w - pi.w));
    }
    __syncthreads();
    for (int t = threadIdx.x; t < BSZ; t += 512) {
        int p = base + t;
        if (p < N) out[p] = acc[t];
    }
}

// ------------------------------------------------- fallback (atomic path) ---
__global__ __launch_bounds__(256) void xsph_edge_kernel(
    const float* __restrict__ fc_p, const float* __restrict__ area,
    const float* __restrict__ density, const float* __restrict__ restDensity,
    const float* __restrict__ velocity, const float* __restrict__ rad,
    const void* __restrict__ nbr, const float* __restrict__ support_p,
    const int* __restrict__ flag, float* __restrict__ out, int E)
{
    const int is64 = *flag;
    const float fc = fc_p[0];
    const float h = support_p[0];
    const float C = 7.0f / ((float)M_PI * h * h);
    const long long e0 =
        (long long)(blockIdx.x * (long long)blockDim.x + threadIdx.x) * 4;
    if (e0 >= (long long)E) return;
    int ii[4], jj[4];
    if (is64) {
        const long long* ni = (const long long*)nbr;
        const long long* nj = ni + E;
#pragma unroll
        for (int k = 0; k < 4; ++k) { ii[k] = (int)ni[e0 + k]; jj[k] = (int)nj[e0 + k]; }
    } else {
        const int* ni = (const int*)nbr;
        const int* nj = ni + E;
        int4 iv = *(const int4*)(ni + e0);
        int4 jv = *(const int4*)(nj + e0);
        ii[0] = iv.x; ii[1] = iv.y; ii[2] = iv.z; ii[3] = iv.w;
        jj[0] = jv.x; jj[1] = jv.y; jj[2] = jv.z; jj[3] = jv.w;
    }
    float4 qv = *(const float4*)(rad + e0);
    float qq[4] = {qv.x, qv.y, qv.z, qv.w};
#pragma unroll
    for (int k = 0; k < 4; ++k) {
        const int i = ii[k], j = jj[k];
        const float rDi = restDensity[i], rDj = restDensity[j];
        const float fac = fc * rDj * area[j];
        const float rho_i = density[i] * rDi, rho_j = density[j] * rDj;
        const float2 vi = *(const float2*)(velocity + 2 * i);
        const float2 vj = *(const float2*)(velocity + 2 * j);
        const float q = qq[k];
        const float b = fmaxf(1.0f - q, 0.0f);
        const float b2 = b * b;
        const float w = C * (b2 * b2) * fmaf(4.0f, q, 1.0f);
        const float s = fac * 2.0f * w / (rho_i + rho_j);
        unsafeAtomicAdd(&out[2 * i],     s * (vj.x - vi.x));
        unsafeAtomicAdd(&out[2 * i + 1], s * (vj.y - vi.y));
    }
}

// ------------------------------------------------------------------ host ----
extern "C" void kernel_launch(void* const* d_in, const int* in_sizes, int n_in,
                              void* d_out, int out_size, void* d_ws, size_t ws_size,
                              hipStream_t stream) {
    const float* fc          = (const float*)d_in[0];
    const float* area        = (const float*)d_in[1];
    const float* density     = (const float*)d_in[2];
    const float* restDensity = (const float*)d_in[3];
    const float* velocity    = (const float*)d_in[4];
    const float* rad         = (const float*)d_in[5];
    const void*  nbr         = d_in[6];
    const float* support     = (const float*)d_in[7];

    const int N = in_sizes[1];
    const int E = in_sizes[5];
    const int NBnum = (N + BSZ - 1) / BSZ;
    const int chunk = (int)(((long long)E + NBLK - 1) / NBLK);

    // ---- workspace layout (16B-aligned sections) ----
    char* ws = (char*)d_ws;
    size_t off = 0;
    int* flag = (int*)(ws + off);               off += 16;
    float4* pre = (float4*)(ws + off);          off += (size_t)N * 16;
    unsigned* table = (unsigned*)(ws + off);    off += (size_t)NBLK * NBnum * 4;
    off = (off + 15) & ~(size_t)15;
    unsigned* toff = (unsigned*)(ws + off);     off += (size_t)NBLK * NBnum * 4;
    off = (off + 15) & ~(size_t)15;
    unsigned* btot = (unsigned*)(ws + off);     off += (size_t)NBnum * 4;
    off = (off + 15) & ~(size_t)15;
    unsigned* bstart = (unsigned*)(ws + off);   off += (size_t)(NBnum + 1) * 4;
    off = (off + 15) & ~(size_t)15;
    int2* jq = (int2*)(ws + off);               off += (size_t)E * 8;
    const size_t need = off;

    detect_idx_width<<<1, 1, 0, stream>>>((const unsigned*)nbr, flag);

    const bool can_sort =
        (ws_size >= need) && (NBnum <= NBK) && (N <= (1 << 22)) &&
        (chunk <= CHUNK) && (E > 0);

    if (can_sort) {
        precompute_particle<<<(N + 255) / 256, 256, 0, stream>>>(
            fc, area, density, restDensity, velocity, pre, N);
        pass_count<<<NBLK, 256, 0, stream>>>(nbr, flag, table, E, chunk, NBnum);
        scan_blocks<<<(NBnum + SCAN_GB - 1) / SCAN_GB, SCAN_TH, 0, stream>>>(
            table, toff, btot, NBnum);
        scan_buckets<<<1, NBnum, 0, stream>>>(btot, bstart, NBnum);
        pass_scatter<<<NBLK, 256, 0, stream>>>(nbr, rad, flag, table, toff,
                                               bstart, jq, E, chunk, NBnum);
        pass_reduce<<<NBnum, 512, 0, stream>>>(jq, pre, bstart, support,
                                               (float2*)d_out, N);
    } else {
        hipMemsetAsync(d_out, 0, (size_t)out_size * sizeof(float), stream);
        const int threads = 256;
        const long long nthreads = ((long long)E + 3) / 4;
        const int blocks = (int)((nthreads + threads - 1) / threads);
        xsph_edge_kernel<<<blocks, threads, 0, stream>>>(
            fc, area, density, restDensity, velocity, rad, nbr, support, flag,
            (float*)d_out, E);
    }
}